// Round 2
// baseline (6477.130 us; speedup 1.0000x reference)
//
#include <hip/hip_runtime.h>

// Problem constants (from reference)
#define NN 50000      // nodes
#define NE 800000     // edges
// IN_DIM = 128, H = 8, D = 16, H*D = 128

// ---------------------------------------------------------------------------
// Kernel 1: fused Q/K/V projection.  grid = ceil(NN/64), block = 384.
// 64-node h-tile staged in LDS; thread tid -> matrix m = tid>>7
// (0=Q,1=K,2=V), column col = tid&127; 64 fp32 accumulators per thread.
// LDS reads are wave-uniform-address (broadcast, conflict-free).
// ---------------------------------------------------------------------------
__global__ __launch_bounds__(384) void qkv_kernel(
    const float* __restrict__ h,
    const float* __restrict__ Wq, const float* __restrict__ bq,
    const float* __restrict__ Wk, const float* __restrict__ bk,
    const float* __restrict__ Wv, const float* __restrict__ bv,
    float* __restrict__ Q, float* __restrict__ K, float* __restrict__ V)
{
    __shared__ float hs[64 * 128];   // 32 KiB
    const int n0 = blockIdx.x * 64;
    const int tid = threadIdx.x;

    // Stage 64x128 fp32 tile -> LDS.  idx in float4 units: row*32 + c4.
    for (int idx = tid; idx < 2048; idx += 384) {
        const int row = idx >> 5;
        const int c4 = idx & 31;
        const int node = n0 + row;
        float4 f = make_float4(0.f, 0.f, 0.f, 0.f);
        if (node < NN)
            f = *((const float4*)(h + (size_t)node * 128) + c4);
        ((float4*)hs)[idx] = f;
    }
    __syncthreads();

    const int m = tid >> 7;     // 0..2
    const int col = tid & 127;
    const float* __restrict__ W = (m == 0) ? Wq : (m == 1) ? Wk : Wv;
    const float* __restrict__ B = (m == 0) ? bq : (m == 1) ? bk : bv;
    float* __restrict__ O = (m == 0) ? Q : (m == 1) ? K : V;

    float acc[64];
#pragma unroll
    for (int n = 0; n < 64; ++n) acc[n] = 0.f;

    const float bias = B[col];

    for (int kk = 0; kk < 128; kk += 4) {
        const float w0 = W[(kk + 0) * 128 + col];
        const float w1 = W[(kk + 1) * 128 + col];
        const float w2 = W[(kk + 2) * 128 + col];
        const float w3 = W[(kk + 3) * 128 + col];
        const float4* hrow = (const float4*)hs + (kk >> 2);
#pragma unroll
        for (int n = 0; n < 64; ++n) {
            float4 hv = hrow[n * 32];   // same addr across wave -> broadcast
            acc[n] = fmaf(hv.x, w0,
                     fmaf(hv.y, w1,
                     fmaf(hv.z, w2,
                     fmaf(hv.w, w3, acc[n]))));
        }
    }

    const int lim = (NN - n0 < 64) ? (NN - n0) : 64;
    for (int n = 0; n < lim; ++n)
        O[(size_t)(n0 + n) * 128 + col] = acc[n] + bias;
}

// ---------------------------------------------------------------------------
// Kernel 2: edge scoring + scatter.  1 thread per (edge, head).
// grid = NE*8/256 = 25000 blocks exactly.
// ---------------------------------------------------------------------------
__global__ __launch_bounds__(256) void edge_kernel(
    const int* __restrict__ src, const int* __restrict__ dst,
    const float* __restrict__ Q, const float* __restrict__ K,
    const float* __restrict__ V,
    float* __restrict__ acc /* [NN,128] */, float* __restrict__ z /* [NN,8] */)
{
    const int gid = blockIdx.x * 256 + threadIdx.x;   // < 6.4M
    const int e = gid >> 3;
    const int hh = gid & 7;

    const int sN = src[e];
    const int dN = dst[e];

    const float4* Kv = (const float4*)K + (size_t)sN * 32 + hh * 4;
    const float4* Qv = (const float4*)Q + (size_t)dN * 32 + hh * 4;

    float sc = 0.f;
#pragma unroll
    for (int j = 0; j < 4; ++j) {
        float4 a = Kv[j], b = Qv[j];
        sc += a.x * b.x + a.y * b.y + a.z * b.z + a.w * b.w;
    }
    sc *= 0.25f;                                   // 1/sqrt(16)
    sc = fminf(5.f, fmaxf(-5.f, sc));              // clip
    const float s = __expf(sc);

    atomicAdd(&z[(size_t)dN * 8 + hh], s);

    const float4* Vv = (const float4*)V + (size_t)sN * 32 + hh * 4;
    float* o = acc + (size_t)dN * 128 + hh * 16;
#pragma unroll
    for (int j = 0; j < 4; ++j) {
        float4 v = Vv[j];
        atomicAdd(o + j * 4 + 0, v.x * s);
        atomicAdd(o + j * 4 + 1, v.y * s);
        atomicAdd(o + j * 4 + 2, v.z * s);
        atomicAdd(o + j * 4 + 3, v.w * s);
    }
}

// ---------------------------------------------------------------------------
// Kernel 3: normalize.  1 thread per 4 output elems (float4).
// ---------------------------------------------------------------------------
__global__ __launch_bounds__(256) void norm_kernel(
    const float* __restrict__ acc, const float* __restrict__ z,
    float* __restrict__ out)
{
    const int gid = blockIdx.x * 256 + threadIdx.x;   // < NN*32 = 1.6M
    if (gid >= NN * 32) return;
    const int n = gid >> 5;
    const int q = gid & 31;        // float4 index within the 128-wide row
    const int hh = q >> 2;         // head = (q*4)/16

    const float inv = 1.0f / (z[(size_t)n * 8 + hh] + 1e-6f);
    float4 a = ((const float4*)acc)[gid];

    float4 r;
    r.x = a.x * inv;
    r.y = a.y * inv;
    r.z = a.z * inv;
    r.w = a.w * inv;
    ((float4*)out)[gid] = r;
}

// ---------------------------------------------------------------------------
extern "C" void kernel_launch(void* const* d_in, const int* in_sizes, int n_in,
                              void* d_out, int out_size, void* d_ws, size_t ws_size,
                              hipStream_t stream)
{
    // Input order: h, e, src, dst, Wq, bq, Wk, bk, We, be, Wv, bv  (all fp32 / int32)
    const float* h  = (const float*)d_in[0];
    // d_in[1] (e), d_in[8] (We), d_in[9] (be) intentionally unused: E_proj is dead code.
    const int* src = (const int*)d_in[2];
    const int* dst = (const int*)d_in[3];
    const float* Wq = (const float*)d_in[4];
    const float* bq = (const float*)d_in[5];
    const float* Wk = (const float*)d_in[6];
    const float* bk = (const float*)d_in[7];
    const float* Wv = (const float*)d_in[10];
    const float* bv = (const float*)d_in[11];

    // Workspace layout (fp32): Q,K,V,acc each NN*128; z = NN*8.  ~104 MB.
    float* Q    = (float*)d_ws;
    float* K    = Q + (size_t)NN * 128;
    float* V    = K + (size_t)NN * 128;
    float* accb = V + (size_t)NN * 128;
    float* z    = accb + (size_t)NN * 128;

    // Zero the accumulators (acc and z are contiguous).
    hipMemsetAsync(accb, 0, ((size_t)NN * 128 + (size_t)NN * 8) * sizeof(float), stream);

    qkv_kernel<<<(NN + 63) / 64, 384, 0, stream>>>(h, Wq, bq, Wk, bk, Wv, bv, Q, K, V);
    edge_kernel<<<(NE * 8) / 256, 256, 0, stream>>>(src, dst, Q, K, V, accb, z);
    norm_kernel<<<(NN * 32 + 255) / 256, 256, 0, stream>>>(accb, z, (float*)d_out);
}

// Round 3
// 987.847 us; speedup vs baseline: 6.5568x; 6.5568x over previous
//
#include <hip/hip_runtime.h>

// Problem constants (from reference)
#define NN 50000      // nodes
#define NE 800000     // edges
// IN_DIM = 128, H = 8, D = 16, H*D = 128

// ---------------------------------------------------------------------------
// Kernel 1: fused Q/K/V projection.  grid = ceil(NN/64), block = 384.
// ---------------------------------------------------------------------------
__global__ __launch_bounds__(384) void qkv_kernel(
    const float* __restrict__ h,
    const float* __restrict__ Wq, const float* __restrict__ bq,
    const float* __restrict__ Wk, const float* __restrict__ bk,
    const float* __restrict__ Wv, const float* __restrict__ bv,
    float* __restrict__ Q, float* __restrict__ K, float* __restrict__ V)
{
    __shared__ float hs[64 * 128];   // 32 KiB
    const int n0 = blockIdx.x * 64;
    const int tid = threadIdx.x;

    for (int idx = tid; idx < 2048; idx += 384) {
        const int row = idx >> 5;
        const int c4 = idx & 31;
        const int node = n0 + row;
        float4 f = make_float4(0.f, 0.f, 0.f, 0.f);
        if (node < NN)
            f = *((const float4*)(h + (size_t)node * 128) + c4);
        ((float4*)hs)[idx] = f;
    }
    __syncthreads();

    const int m = tid >> 7;     // 0..2
    const int col = tid & 127;
    const float* __restrict__ W = (m == 0) ? Wq : (m == 1) ? Wk : Wv;
    const float* __restrict__ B = (m == 0) ? bq : (m == 1) ? bk : bv;
    float* __restrict__ O = (m == 0) ? Q : (m == 1) ? K : V;

    float acc[64];
#pragma unroll
    for (int n = 0; n < 64; ++n) acc[n] = 0.f;

    const float bias = B[col];

    for (int kk = 0; kk < 128; kk += 4) {
        const float w0 = W[(kk + 0) * 128 + col];
        const float w1 = W[(kk + 1) * 128 + col];
        const float w2 = W[(kk + 2) * 128 + col];
        const float w3 = W[(kk + 3) * 128 + col];
        const float4* hrow = (const float4*)hs + (kk >> 2);
#pragma unroll
        for (int n = 0; n < 64; ++n) {
            float4 hv = hrow[n * 32];   // same addr across wave -> broadcast
            acc[n] = fmaf(hv.x, w0,
                     fmaf(hv.y, w1,
                     fmaf(hv.z, w2,
                     fmaf(hv.w, w3, acc[n]))));
        }
    }

    const int lim = (NN - n0 < 64) ? (NN - n0) : 64;
    for (int n = 0; n < lim; ++n)
        O[(size_t)(n0 + n) * 128 + col] = acc[n] + bias;
}

// ---------------------------------------------------------------------------
// CSR build: histogram of dst, exclusive scan, scatter src by dst bucket.
// ---------------------------------------------------------------------------
__global__ __launch_bounds__(256) void hist_kernel(
    const int* __restrict__ dst, int* __restrict__ counts)
{
    const int e = blockIdx.x * 256 + threadIdx.x;
    if (e < NE) atomicAdd(&counts[dst[e]], 1);
}

// Single block, 1024 threads; each thread owns a CHUNK of 49 counters.
#define SCAN_T 1024
#define SCAN_CHUNK 49   // 1024*49 = 50176 >= NN
__global__ __launch_bounds__(SCAN_T) void scan_kernel(
    const int* __restrict__ counts, int* __restrict__ offsets,
    int* __restrict__ cursor)
{
    __shared__ int part[SCAN_T];
    const int t = threadIdx.x;

    int base = t * SCAN_CHUNK;
    int sum = 0;
    for (int j = 0; j < SCAN_CHUNK; ++j) {
        int idx = base + j;
        if (idx < NN) sum += counts[idx];
    }
    part[t] = sum;
    __syncthreads();

    // Hillis-Steele inclusive scan over 1024 partials.
    for (int off = 1; off < SCAN_T; off <<= 1) {
        int v = (t >= off) ? part[t - off] : 0;
        __syncthreads();
        part[t] += v;
        __syncthreads();
    }

    int running = (t == 0) ? 0 : part[t - 1];   // exclusive chunk base
    for (int j = 0; j < SCAN_CHUNK; ++j) {
        int idx = base + j;
        if (idx < NN) {
            offsets[idx] = running;
            cursor[idx]  = running;
            running += counts[idx];
        }
    }
    if (t == SCAN_T - 1) offsets[NN] = part[SCAN_T - 1];
}

__global__ __launch_bounds__(256) void scatter_kernel(
    const int* __restrict__ src, const int* __restrict__ dst,
    int* __restrict__ cursor, int* __restrict__ src_sorted)
{
    const int e = blockIdx.x * 256 + threadIdx.x;
    if (e < NE) {
        const int pos = atomicAdd(&cursor[dst[e]], 1);
        src_sorted[pos] = src[e];
    }
}

// ---------------------------------------------------------------------------
// Aggregate: one thread per (node, head).  Gather-only — zero fp32 atomics.
// Lanes n*8+h (h=0..7) walk the same edge segment in lockstep and together
// cover a full contiguous 512B K/V row per shared src.
// ---------------------------------------------------------------------------
__global__ __launch_bounds__(256) void aggregate_kernel(
    const int* __restrict__ offsets, const int* __restrict__ src_sorted,
    const float* __restrict__ Q, const float* __restrict__ K,
    const float* __restrict__ V, float* __restrict__ out)
{
    const int gid = blockIdx.x * 256 + threadIdx.x;   // < NN*8
    if (gid >= NN * 8) return;
    const int n = gid >> 3;
    const int hh = gid & 7;

    const float4* Qv = (const float4*)Q + (size_t)n * 32 + hh * 4;
    float4 q0 = Qv[0], q1 = Qv[1], q2 = Qv[2], q3 = Qv[3];

    float4 a0 = make_float4(0.f, 0.f, 0.f, 0.f);
    float4 a1 = a0, a2 = a0, a3 = a0;
    float z = 0.f;

    const int beg = offsets[n];
    const int end = offsets[n + 1];

    for (int i = beg; i < end; ++i) {
        const int s = src_sorted[i];
        const float4* Kv = (const float4*)K + (size_t)s * 32 + hh * 4;
        float4 k0 = Kv[0], k1 = Kv[1], k2 = Kv[2], k3 = Kv[3];

        float sc = k0.x * q0.x + k0.y * q0.y + k0.z * q0.z + k0.w * q0.w
                 + k1.x * q1.x + k1.y * q1.y + k1.z * q1.z + k1.w * q1.w
                 + k2.x * q2.x + k2.y * q2.y + k2.z * q2.z + k2.w * q2.w
                 + k3.x * q3.x + k3.y * q3.y + k3.z * q3.z + k3.w * q3.w;
        sc *= 0.25f;                          // 1/sqrt(16)
        sc = fminf(5.f, fmaxf(-5.f, sc));
        const float sw = __expf(sc);
        z += sw;

        const float4* Vv = (const float4*)V + (size_t)s * 32 + hh * 4;
        float4 v0 = Vv[0], v1 = Vv[1], v2 = Vv[2], v3 = Vv[3];
        a0.x = fmaf(sw, v0.x, a0.x); a0.y = fmaf(sw, v0.y, a0.y);
        a0.z = fmaf(sw, v0.z, a0.z); a0.w = fmaf(sw, v0.w, a0.w);
        a1.x = fmaf(sw, v1.x, a1.x); a1.y = fmaf(sw, v1.y, a1.y);
        a1.z = fmaf(sw, v1.z, a1.z); a1.w = fmaf(sw, v1.w, a1.w);
        a2.x = fmaf(sw, v2.x, a2.x); a2.y = fmaf(sw, v2.y, a2.y);
        a2.z = fmaf(sw, v2.z, a2.z); a2.w = fmaf(sw, v2.w, a2.w);
        a3.x = fmaf(sw, v3.x, a3.x); a3.y = fmaf(sw, v3.y, a3.y);
        a3.z = fmaf(sw, v3.z, a3.z); a3.w = fmaf(sw, v3.w, a3.w);
    }

    const float inv = 1.0f / (z + 1e-6f);
    a0.x *= inv; a0.y *= inv; a0.z *= inv; a0.w *= inv;
    a1.x *= inv; a1.y *= inv; a1.z *= inv; a1.w *= inv;
    a2.x *= inv; a2.y *= inv; a2.z *= inv; a2.w *= inv;
    a3.x *= inv; a3.y *= inv; a3.z *= inv; a3.w *= inv;

    float4* O = (float4*)out + (size_t)n * 32 + hh * 4;
    O[0] = a0; O[1] = a1; O[2] = a2; O[3] = a3;
}

// ---------------------------------------------------------------------------
extern "C" void kernel_launch(void* const* d_in, const int* in_sizes, int n_in,
                              void* d_out, int out_size, void* d_ws, size_t ws_size,
                              hipStream_t stream)
{
    // Input order: h, e, src, dst, Wq, bq, Wk, bk, We, be, Wv, bv  (fp32 / int32)
    const float* h  = (const float*)d_in[0];
    // d_in[1] (e), d_in[8] (We), d_in[9] (be) unused: E_proj is dead code.
    const int* src = (const int*)d_in[2];
    const int* dst = (const int*)d_in[3];
    const float* Wq = (const float*)d_in[4];
    const float* bq = (const float*)d_in[5];
    const float* Wk = (const float*)d_in[6];
    const float* bk = (const float*)d_in[7];
    const float* Wv = (const float*)d_in[10];
    const float* bv = (const float*)d_in[11];

    // Workspace: Q,K,V fp32 (76.8 MB) then int CSR arrays (~3.6 MB).
    float* Q = (float*)d_ws;
    float* K = Q + (size_t)NN * 128;
    float* V = K + (size_t)NN * 128;
    int* counts     = (int*)(V + (size_t)NN * 128);
    int* cursor     = counts + NN;
    int* offsets    = cursor + NN;          // NN+1 entries
    int* src_sorted = offsets + (NN + 1);   // NE entries

    hipMemsetAsync(counts, 0, NN * sizeof(int), stream);

    qkv_kernel<<<(NN + 63) / 64, 384, 0, stream>>>(h, Wq, bq, Wk, bk, Wv, bv, Q, K, V);
    hist_kernel<<<(NE + 255) / 256, 256, 0, stream>>>(dst, counts);
    scan_kernel<<<1, SCAN_T, 0, stream>>>(counts, offsets, cursor);
    scatter_kernel<<<(NE + 255) / 256, 256, 0, stream>>>(src, dst, cursor, src_sorted);
    aggregate_kernel<<<(NN * 8 + 255) / 256, 256, 0, stream>>>(offsets, src_sorted, Q, K, V, (float*)d_out);
}